// Round 5
// baseline (285.877 us; speedup 1.0000x reference)
//
#include <hip/hip_runtime.h>
#include <math.h>

// SMorphLayer: B=8, C=1, H=W=128, F=16, KH=KW=5, stride 1 -> OH=OW=124
// y[b,f,oy,ox] = sm(p + k1[f]) + sm(-p + k2[f]) + bias[f],
// sm(t) = sum(t e^t)/sum(e^t) (alpha=1, max-shift cancels exactly).
// Factorization: e^{p_j+k1_fj} = E_j*e1_fj, E_j=e^{p_j}, I_j=e^{-p_j}:
//   n1 = sum_j fma(p, e1, k1e1)*E   d1 = sum_j E*e1
//   n2 = sum_j fma(-p, e2, k2e2)*I  d2 = sum_j I*e2
//
// Round-4: round-3's PX=4/FPB=4 spilled (VGPR=256, 192MB scratch writes).
// Keep PX=4 amortization, drop to FPB=2 (FSPLIT=8): 32 accumulators,
// live set ~80 VGPR, enforced by __launch_bounds__(256, 4) (<=128 VGPR,
// 4 blocks/CU -> the whole 1024-block grid co-resident).

#define Bn 8
#define Fn 16
#define Hn 128
#define Wn 128
#define OHn 124
#define OWn 124
#define FSPLIT 8
#define FPB (Fn / FSPLIT)   // 2 filters per block
#define ROWS 8              // output rows per block
#define TW 132              // tile row stride in floats (16B aligned)
#define TR 12               // tile rows (8 + 4)

__global__ __launch_bounds__(256, 4) void smorph_fused(
    const float* __restrict__ x, const float* __restrict__ k1,
    const float* __restrict__ k2, const float* __restrict__ bias,
    float* __restrict__ out) {
  __shared__ float tile[TR][TW];   // 12 x 132 x 4B = 6336 B
  __shared__ float4 ccs[FPB * 25]; // 800 B: {e1, k1*e1, e2, k2*e2}
  __shared__ float bs[FPB];

  const int z = blockIdx.z;
  const int b = z >> 3, fh = z & 7;
  const int y0 = blockIdx.y * ROWS;
  const int tid = threadIdx.x;
  const float* xb = x + b * (Hn * Wn);

  // Stage 12x132 input tile as float4 (zero-pad outside image).
  for (int i = tid; i < TR * (TW / 4); i += 256) {
    const int r = i / (TW / 4), c4 = i % (TW / 4);
    const int gy = y0 + r, gx = c4 * 4;
    float4 v = make_float4(0.f, 0.f, 0.f, 0.f);
    if (gy < Hn && gx < Wn) v = *(const float4*)&xb[gy * Wn + gx];
    *(float4*)&tile[r][gx] = v;
  }
  // This block's 2 filters' constant table (50 entries).
  if (tid < FPB * 25) {
    const int gi = fh * (FPB * 25) + tid;
    const float a = k1[gi], c = k2[gi];
    const float e1 = __expf(a), e2 = __expf(c);
    ccs[tid] = make_float4(e1, a * e1, e2, c * e2);
  }
  if (tid < FPB) bs[tid] = bias[fh * FPB + tid];
  __syncthreads();

  const int xi = tid & 31;   // leftmost output col = 4*xi
  const int ly = tid >> 5;   // output row within block
  const int oy = y0 + ly;
  if (oy >= OHn || xi >= 31) return;  // no barriers below; tail threads idle

  float n1[FPB][4], d1[FPB][4], n2[FPB][4], d2[FPB][4];
#pragma unroll
  for (int fi = 0; fi < FPB; ++fi)
#pragma unroll
    for (int q = 0; q < 4; ++q) {
      n1[fi][q] = 0.f; d1[fi][q] = 0.f; n2[fi][q] = 0.f; d2[fi][q] = 0.f;
    }

#pragma unroll
  for (int kh = 0; kh < 5; ++kh) {
    // 8 row floats cover all kw+q (kw 0..4, q 0..3): 2 aligned b128 reads.
    const float* rowp = &tile[ly + kh][xi * 4];
    const float4 ra = *(const float4*)rowp;
    const float4 rb = *(const float4*)(rowp + 4);
    const float r[8] = {ra.x, ra.y, ra.z, ra.w, rb.x, rb.y, rb.z, rb.w};
    float Er[8], Ir[8];
#pragma unroll
    for (int c = 0; c < 8; ++c) {
      Er[c] = __expf(r[c]);
      Ir[c] = __expf(-r[c]);
    }
#pragma unroll
    for (int kw = 0; kw < 5; ++kw) {
      const int j = kh * 5 + kw;
#pragma unroll
      for (int fi = 0; fi < FPB; ++fi) {
        const float4 v = ccs[fi * 25 + j];  // wave-uniform broadcast b128
#pragma unroll
        for (int q = 0; q < 4; ++q) {
          const float p = r[kw + q], E = Er[kw + q], I = Ir[kw + q];
          const float t1 = fmaf(p, v.x, v.y);
          n1[fi][q] = fmaf(t1, E, n1[fi][q]);
          d1[fi][q] = fmaf(E, v.x, d1[fi][q]);
          const float t2 = fmaf(-p, v.z, v.w);
          n2[fi][q] = fmaf(t2, I, n2[fi][q]);
          d2[fi][q] = fmaf(I, v.z, d2[fi][q]);
        }
      }
    }
  }

#pragma unroll
  for (int fi = 0; fi < FPB; ++fi) {
    const float bv = bs[fi];
    float4 o;
    o.x = __fdividef(n1[fi][0], d1[fi][0]) + __fdividef(n2[fi][0], d2[fi][0]) + bv;
    o.y = __fdividef(n1[fi][1], d1[fi][1]) + __fdividef(n2[fi][1], d2[fi][1]) + bv;
    o.z = __fdividef(n1[fi][2], d1[fi][2]) + __fdividef(n2[fi][2], d2[fi][2]) + bv;
    o.w = __fdividef(n1[fi][3], d1[fi][3]) + __fdividef(n2[fi][3], d2[fi][3]) + bv;
    *(float4*)&out[((b * Fn + fh * FPB + fi) * OHn + oy) * OWn + xi * 4] = o;
  }
}

extern "C" void kernel_launch(void* const* d_in, const int* in_sizes, int n_in,
                              void* d_out, int out_size, void* d_ws, size_t ws_size,
                              hipStream_t stream) {
  const float* x    = (const float*)d_in[0];
  const float* k1   = (const float*)d_in[1];
  const float* k2   = (const float*)d_in[2];
  const float* bias = (const float*)d_in[3];
  float* out = (float*)d_out;

  dim3 grid(1, (OHn + ROWS - 1) / ROWS, Bn * FSPLIT);  // (1, 16, 64)
  smorph_fused<<<grid, 256, 0, stream>>>(x, k1, k2, bias, out);
}

// Round 6
// 16.924 us; speedup vs baseline: 16.8919x; 16.8919x over previous
//
#include <hip/hip_runtime.h>
#include <math.h>

// SMorphLayer: B=8, C=1, H=W=128, F=16, KH=KW=5, stride 1 -> OH=OW=124
// y[b,f,oy,ox] = sm(p + k1[f]) + sm(-p + k2[f]) + bias[f],
// sm(t) = sum(t e^t)/sum(e^t) (alpha=1, max-shift cancels exactly).
// Factorization: e^{p_j+k1_fj} = E_j*e1_fj, E_j=e^{p_j}, I_j=e^{-p_j}:
//   n1 = sum_j fma(p, e1, k1e1)*E   d1 = sum_j E*e1
//   n2 = sum_j fma(-p, e2, k2e2)*I  d2 = sum_j I*e2
//
// Round-5: round-4's __launch_bounds__(256,4) made the allocator target
// 64 VGPRs (512/8 waves-per-eu upper bound) -> total spill catastrophe.
// Round-3's FPB=4 was genuinely too fat once the full 5x5 unroll let the
// scheduler hoist all constant loads. Fix: FPB=2 + PLAIN launch_bounds +
// '#pragma unroll 1' on the kh loop so at most one kh's constants (10
// float4) are hoisted. Live set ~= 32 acc + 24 row/exp + ~10 const + addr
// ~= 110 VGPR -> no spills, 4 blocks/CU naturally.

#define Bn 8
#define Fn 16
#define Hn 128
#define Wn 128
#define OHn 124
#define OWn 124
#define FSPLIT 8
#define FPB (Fn / FSPLIT)   // 2 filters per block
#define ROWS 8              // output rows per block
#define TW 132              // tile row stride in floats (16B aligned)
#define TR 12               // tile rows (8 + 4)

__global__ __launch_bounds__(256) void smorph_fused(
    const float* __restrict__ x, const float* __restrict__ k1,
    const float* __restrict__ k2, const float* __restrict__ bias,
    float* __restrict__ out) {
  __shared__ float tile[TR][TW];   // 12 x 132 x 4B = 6336 B
  __shared__ float4 ccs[FPB * 25]; // 800 B: {e1, k1*e1, e2, k2*e2}
  __shared__ float bs[FPB];

  const int z = blockIdx.z;
  const int b = z >> 3, fh = z & 7;
  const int y0 = blockIdx.y * ROWS;
  const int tid = threadIdx.x;
  const float* xb = x + b * (Hn * Wn);

  // Stage 12x132 input tile as float4 (zero-pad outside image).
  for (int i = tid; i < TR * (TW / 4); i += 256) {
    const int r = i / (TW / 4), c4 = i % (TW / 4);
    const int gy = y0 + r, gx = c4 * 4;
    float4 v = make_float4(0.f, 0.f, 0.f, 0.f);
    if (gy < Hn && gx < Wn) v = *(const float4*)&xb[gy * Wn + gx];
    *(float4*)&tile[r][gx] = v;
  }
  // This block's 2 filters' constant table (50 entries).
  if (tid < FPB * 25) {
    const int gi = fh * (FPB * 25) + tid;
    const float a = k1[gi], c = k2[gi];
    const float e1 = __expf(a), e2 = __expf(c);
    ccs[tid] = make_float4(e1, a * e1, e2, c * e2);
  }
  if (tid < FPB) bs[tid] = bias[fh * FPB + tid];
  __syncthreads();

  const int xi = tid & 31;   // leftmost output col = 4*xi
  const int ly = tid >> 5;   // output row within block
  const int oy = y0 + ly;
  if (oy >= OHn || xi >= 31) return;  // no barriers below; tail threads idle

  float n1[FPB][4], d1[FPB][4], n2[FPB][4], d2[FPB][4];
#pragma unroll
  for (int fi = 0; fi < FPB; ++fi)
#pragma unroll
    for (int q = 0; q < 4; ++q) {
      n1[fi][q] = 0.f; d1[fi][q] = 0.f; n2[fi][q] = 0.f; d2[fi][q] = 0.f;
    }

#pragma unroll 1  // keep kh a real loop: blocks cross-kh hoist of ccs loads
  for (int kh = 0; kh < 5; ++kh) {
    // 8 row floats cover all kw+q (kw 0..4, q 0..3): 2 aligned b128 reads.
    const float* rowp = &tile[ly + kh][xi * 4];
    const float4 ra = *(const float4*)rowp;
    const float4 rb = *(const float4*)(rowp + 4);
    const float r[8] = {ra.x, ra.y, ra.z, ra.w, rb.x, rb.y, rb.z, rb.w};
    float Er[8], Ir[8];
#pragma unroll
    for (int c = 0; c < 8; ++c) {
      Er[c] = __expf(r[c]);
      Ir[c] = __expf(-r[c]);
    }
#pragma unroll
    for (int kw = 0; kw < 5; ++kw) {
#pragma unroll
      for (int fi = 0; fi < FPB; ++fi) {
        const float4 v = ccs[fi * 25 + kh * 5 + kw];  // uniform broadcast
#pragma unroll
        for (int q = 0; q < 4; ++q) {
          const float p = r[kw + q], E = Er[kw + q], I = Ir[kw + q];
          const float t1 = fmaf(p, v.x, v.y);
          n1[fi][q] = fmaf(t1, E, n1[fi][q]);
          d1[fi][q] = fmaf(E, v.x, d1[fi][q]);
          const float t2 = fmaf(-p, v.z, v.w);
          n2[fi][q] = fmaf(t2, I, n2[fi][q]);
          d2[fi][q] = fmaf(I, v.z, d2[fi][q]);
        }
      }
    }
  }

#pragma unroll
  for (int fi = 0; fi < FPB; ++fi) {
    const float bv = bs[fi];
    float4 o;
    o.x = __fdividef(n1[fi][0], d1[fi][0]) + __fdividef(n2[fi][0], d2[fi][0]) + bv;
    o.y = __fdividef(n1[fi][1], d1[fi][1]) + __fdividef(n2[fi][1], d2[fi][1]) + bv;
    o.z = __fdividef(n1[fi][2], d1[fi][2]) + __fdividef(n2[fi][2], d2[fi][2]) + bv;
    o.w = __fdividef(n1[fi][3], d1[fi][3]) + __fdividef(n2[fi][3], d2[fi][3]) + bv;
    *(float4*)&out[((b * Fn + fh * FPB + fi) * OHn + oy) * OWn + xi * 4] = o;
  }
}

extern "C" void kernel_launch(void* const* d_in, const int* in_sizes, int n_in,
                              void* d_out, int out_size, void* d_ws, size_t ws_size,
                              hipStream_t stream) {
  const float* x    = (const float*)d_in[0];
  const float* k1   = (const float*)d_in[1];
  const float* k2   = (const float*)d_in[2];
  const float* bias = (const float*)d_in[3];
  float* out = (float*)d_out;

  dim3 grid(1, (OHn + ROWS - 1) / ROWS, Bn * FSPLIT);  // (1, 16, 64)
  smorph_fused<<<grid, 256, 0, stream>>>(x, k1, k2, bias, out);
}